// Round 7
// baseline (73.909 us; speedup 1.0000x reference)
//
#include <hip/hip_runtime.h>
#include <hip/hip_bf16.h>

#define HC 60
#define WCC 60
#define DD 64
#define NCELL (HC * WCC)      // 3600
#define NBC (4 * NCELL)       // 14400
#define IMG (HC * 8)          // 480
#define MPAD 3840             // 60 * 64 zero-padded rows per batch
#define NXT 60                // 64-row tiles per dim
#define NTILES (NXT * NXT * 4)   // 14400 wave-tiles
#define GB 768                // gemm blocks (3/CU)
#define NWAVES (GB * 4)       // 3072

#define CVT_BLOCKS 480        // 4*3840*64/8 / 256
#define VM_BLOCKS 57          // ceil(14400/256)
#define WC_BLOCKS 60          // 4*3840/256
#define PREP_BLOCKS (CVT_BLOCKS + VM_BLOCKS + WC_BLOCKS)   // 597

typedef __bf16 bf16x8 __attribute__((ext_vector_type(8)));
typedef float f32x4 __attribute__((ext_vector_type(4)));
typedef unsigned short u16x8 __attribute__((ext_vector_type(8)));

__device__ inline unsigned short f2bf(float f) {
    union { float f; unsigned u; } x; x.f = f;
    unsigned u = x.u;
    unsigned r = (u + 0x7fffu + ((u >> 16) & 1u)) >> 16;  // RNE
    return (unsigned short)r;
}

__device__ inline int div60(int v) { return (v * 17477) >> 20; }  // exact for 0<=v<3840

// ---- kernel 1 (fused prep): f32->bf16 convert (padded), vm + partial sum, warped centers ----
__global__ __launch_bounds__(256) void dl_prep_kernel(
    const float* __restrict__ desc, const float* __restrict__ wdesc,
    const float* __restrict__ homog, const float* __restrict__ mask,
    unsigned short* __restrict__ descb, unsigned short* __restrict__ wdescb,
    float* __restrict__ vm, float* __restrict__ vpart, float2* __restrict__ wcent,
    unsigned int* __restrict__ done)
{
    const int bid = blockIdx.x;
    const int tid = threadIdx.x;

    if (bid < CVT_BLOCKS) {
        int t = bid * 256 + tid;
        int brow = t >> 3;
        int col = (t & 7) * 8;
        int b = brow / MPAD;
        int row = brow - b * MPAD;
        u16x8 oa = (u16x8)0, ob = (u16x8)0;
        if (row < NCELL) {
            size_t src = ((size_t)(b * NCELL + row)) * DD + col;
            float4 a0 = *(const float4*)(desc + src);
            float4 a1 = *(const float4*)(desc + src + 4);
            float4 b0 = *(const float4*)(wdesc + src);
            float4 b1 = *(const float4*)(wdesc + src + 4);
            oa[0] = f2bf(a0.x); oa[1] = f2bf(a0.y); oa[2] = f2bf(a0.z); oa[3] = f2bf(a0.w);
            oa[4] = f2bf(a1.x); oa[5] = f2bf(a1.y); oa[6] = f2bf(a1.z); oa[7] = f2bf(a1.w);
            ob[0] = f2bf(b0.x); ob[1] = f2bf(b0.y); ob[2] = f2bf(b0.z); ob[3] = f2bf(b0.w);
            ob[4] = f2bf(b1.x); ob[5] = f2bf(b1.y); ob[6] = f2bf(b1.z); ob[7] = f2bf(b1.w);
        }
        size_t dst = (size_t)brow * DD + col;
        *(u16x8*)(descb + dst) = oa;
        *(u16x8*)(wdescb + dst) = ob;
    } else if (bid < CVT_BLOCKS + VM_BLOCKS) {
        int vb = bid - CVT_BLOCKS;
        int cell = vb * 256 + tid;
        float v = 0.f;
        if (cell < NBC) {
            int b = cell / NCELL;
            int rem = cell % NCELL;
            int k = rem / WCC, l = rem % WCC;
            const float* p = mask + (size_t)b * IMG * IMG + (size_t)(k * 8) * IMG + l * 8;
            float prod = 1.f;
#pragma unroll
            for (int dy = 0; dy < 8; ++dy) {
                float4 a0 = *(const float4*)(p + (size_t)dy * IMG);
                float4 a1 = *(const float4*)(p + (size_t)dy * IMG + 4);
                prod *= a0.x * a0.y * a0.z * a0.w * a1.x * a1.y * a1.z * a1.w;
            }
            vm[cell] = prod;
            v = prod;
        }
#pragma unroll
        for (int off = 32; off > 0; off >>= 1) v += __shfl_xor(v, off);
        __shared__ float sp[4];
        if ((tid & 63) == 0) sp[tid >> 6] = v;
        __syncthreads();
        if (tid == 0) vpart[vb] = sp[0] + sp[1] + sp[2] + sp[3];
    } else {
        if (bid == CVT_BLOCKS + VM_BLOCKS && tid == 0) *done = 0u;  // reset finale counter
        int t = (bid - CVT_BLOCKS - VM_BLOCKS) * 256 + tid;   // 0 .. 15359
        int b = t / MPAD;
        int r = t - b * MPAD;
        float2 o;
        if (r < NCELL) {
            int i = div60(r);
            int j = r - i * WCC;
            const float* H = homog + b * 9;
            float x = (float)(j * 8 + 4), y = (float)(i * 8 + 4);
            float X2 = H[6] * x + H[7] * y + H[8];
            o.x = (H[3] * x + H[4] * y + H[5]) / X2;   // wy
            o.y = (H[0] * x + H[1] * y + H[2]) / X2;   // wx
        } else {
            o.x = 1e9f; o.y = 1e9f;                    // pad rows: s = 0 path
        }
        wcent[t] = o;
    }
}

// ---- kernel 2: barrier-free direct-to-register MFMA GEMM + fused loss + finale ----
// Each wave owns 64x64 output tiles; A fragments register-resident across its tile span.
__global__ __launch_bounds__(256, 3) void dl_gemm_loss_kernel(
    const unsigned short* __restrict__ descb, const unsigned short* __restrict__ wdescb,
    const float* __restrict__ vm, const float2* __restrict__ wcent,
    const float* __restrict__ vpart,
    float* __restrict__ gpart, unsigned int* __restrict__ done,
    float* __restrict__ out)
{
    __shared__ float sred[4];
    __shared__ float sl[4], sv[4];
    __shared__ unsigned int slast;

    const int tid = threadIdx.x;
    const int lane = tid & 63;
    const int wv = tid >> 6;
    const int w = blockIdx.x * 4 + wv;              // 0 .. 3071
    const int t0 = (NTILES * w) / NWAVES;
    const int t1 = (NTILES * (w + 1)) / NWAVES;

    const int frow = lane & 15;
    const int kg = (lane >> 4) * 16;                // byte offset of lane's k-group

    bf16x8 afr[2][4];
    float partial = 0.f;
    float wlo = 0.f, whi = 0.f;
    int curax = -1;
    int xb = 0, bb = 0;                              // current A panel (row base, batch)

    for (int t = t0; t < t1; ++t) {
        int b = t / (NXT * NXT);
        int r = t - b * (NXT * NXT);
        int x = r / NXT;
        int y = r - x * NXT;

        if (b * 64 + x != curax) {
            curax = b * 64 + x;
            bb = b; xb = x * 64;
            const unsigned char* gA = (const unsigned char*)descb
                                      + ((size_t)b * MPAD + xb) * 128;
#pragma unroll
            for (int kk = 0; kk < 2; ++kk)
#pragma unroll
                for (int f = 0; f < 4; ++f)
                    afr[kk][f] = *(const bf16x8*)(gA + (size_t)(f * 16 + frow) * 128
                                                  + kk * 64 + kg);
            float wy = wcent[b * MPAD + xb + lane].x;
            wlo = wy; whi = wy;
#pragma unroll
            for (int off = 32; off > 0; off >>= 1) {
                wlo = fminf(wlo, __shfl_xor(wlo, off));
                whi = fmaxf(whi, __shfl_xor(whi, off));
            }
        }

        const unsigned char* gB = (const unsigned char*)wdescb
                                  + ((size_t)b * MPAD + y * 64) * 128;

        // col geometry + vm (independent of matrix loads)
        int n0 = y * 64;
        float cyv[4], cxv[4], vmv[4];
#pragma unroll
        for (int fj = 0; fj < 4; ++fj) {
            int col = n0 + fj * 16 + frow;
            int k = div60(col);
            int l = col - k * WCC;
            cyv[fj] = (float)(k * 8 + 4);
            cxv[fj] = (float)(l * 8 + 4);
            vmv[fj] = (col < NCELL) ? vm[b * NCELL + col] : 0.f;
        }
        float cy0 = (float)(div60(n0) * 8 + 4) - 7.5f;
        float cy1 = (float)(div60(n0 + 63) * 8 + 4) + 7.5f;
        bool full = (whi >= cy0) && (wlo <= cy1);

        f32x4 acc[4][4];
        bf16x8 bfr[4];
        const f32x4 Z = (f32x4)(0.f);
#pragma unroll
        for (int f = 0; f < 4; ++f)
            bfr[f] = *(const bf16x8*)(gB + (size_t)(f * 16 + frow) * 128 + kg);
#pragma unroll
        for (int fi = 0; fi < 4; ++fi)
#pragma unroll
            for (int fj = 0; fj < 4; ++fj)
                acc[fi][fj] = __builtin_amdgcn_mfma_f32_16x16x32_bf16(
                    afr[0][fi], bfr[fj], Z, 0, 0, 0);
#pragma unroll
        for (int f = 0; f < 4; ++f)
            bfr[f] = *(const bf16x8*)(gB + (size_t)(f * 16 + frow) * 128 + 64 + kg);
#pragma unroll
        for (int fi = 0; fi < 4; ++fi)
#pragma unroll
            for (int fj = 0; fj < 4; ++fj)
                acc[fi][fj] = __builtin_amdgcn_mfma_f32_16x16x32_bf16(
                    afr[1][fi], bfr[fj], acc[fi][fj], 0, 0, 0);

        // max-form epilogue: vm*max(dot,0.2); s=1 -> vm*(250*relu(1-dot)+0.2)
        if (full) {
#pragma unroll
            for (int fi = 0; fi < 4; ++fi) {
#pragma unroll
                for (int q = 0; q < 4; ++q) {
                    float2 w2 = wcent[bb * MPAD + xb + fi * 16 + (lane >> 4) * 4 + q];
#pragma unroll
                    for (int fj = 0; fj < 4; ++fj) {
                        float dot = acc[fi][fj][q];
                        float ddy = cyv[fj] - w2.x;
                        float ddx = cxv[fj] - w2.y;
                        float d2 = ddy * ddy + ddx * ddx;
                        float pos = 250.f * fmaxf(1.f - dot, 0.f) + 0.2f;
                        float neg = fmaxf(dot, 0.2f);
                        partial += vmv[fj] * ((d2 <= 56.25f) ? pos : neg);
                    }
                }
            }
        } else {
#pragma unroll
            for (int fj = 0; fj < 4; ++fj) {
                float cs = 0.f;
#pragma unroll
                for (int fi = 0; fi < 4; ++fi)
#pragma unroll
                    for (int q = 0; q < 4; ++q)
                        cs += fmaxf(acc[fi][fj][q], 0.2f);
                partial = fmaf(vmv[fj], cs, partial);
            }
        }
    }

    // block reduction -> gpart; last finished block computes the scalar
#pragma unroll
    for (int off = 32; off > 0; off >>= 1) partial += __shfl_xor(partial, off);
    if (lane == 0) sred[wv] = partial;
    __syncthreads();
    if (tid == 0) {
        gpart[blockIdx.x] = sred[0] + sred[1] + sred[2] + sred[3];
        __threadfence();
        slast = atomicAdd(done, 1u);
    }
    __syncthreads();
    if (slast == GB - 1) {
        __threadfence();
        float ls = 0.f, vs = 0.f;
        for (int i = tid; i < GB; i += 256) ls += gpart[i];
        for (int i = tid; i < VM_BLOCKS; i += 256) vs += vpart[i];
#pragma unroll
        for (int off = 32; off > 0; off >>= 1) {
            ls += __shfl_xor(ls, off);
            vs += __shfl_xor(vs, off);
        }
        if ((tid & 63) == 0) { sl[tid >> 6] = ls; sv[tid >> 6] = vs; }
        __syncthreads();
        if (tid == 0) {
            float L = sl[0] + sl[1] + sl[2] + sl[3];
            float V = sv[0] + sv[1] + sv[2] + sv[3];
            L -= 0.2f * (float)MPAD * V;      // max-form global correction
            out[0] = L / (V * (float)NCELL);
        }
    }
}

extern "C" void kernel_launch(void* const* d_in, const int* in_sizes, int n_in,
                              void* d_out, int out_size, void* d_ws, size_t ws_size,
                              hipStream_t stream) {
    const float* desc  = (const float*)d_in[0];
    const float* wdesc = (const float*)d_in[1];
    const float* homog = (const float*)d_in[2];
    const float* mask  = (const float*)d_in[3];
    float* out = (float*)d_out;
    float* wsf = (float*)d_ws;

    // workspace layout (floats); every slot overwritten (or reset by prep) each call
    float* vpart = wsf;                           // [57]
    float* vm    = wsf + 64;                      // [14400]
    float* gpart = wsf + 64 + NBC;                // [768]
    unsigned int* done = (unsigned int*)(wsf + 15296);
    float2* wcent = (float2*)(wsf + 15304);       // [4*3840] float2
    unsigned short* descb  = (unsigned short*)(wsf + 46080);   // bf16 [4*3840*64]
    unsigned short* wdescb = descb + (size_t)4 * MPAD * DD;

    hipLaunchKernelGGL(dl_prep_kernel, dim3(PREP_BLOCKS), dim3(256), 0, stream,
                       desc, wdesc, homog, mask, descb, wdescb, vm, vpart, wcent, done);
    hipLaunchKernelGGL(dl_gemm_loss_kernel, dim3(GB), dim3(256), 0, stream,
                       descb, wdescb, vm, wcent, vpart, gpart, done, out);
}